// Round 3
// baseline (184.183 us; speedup 1.0000x reference)
//
#include <hip/hip_runtime.h>
#include <math.h>

#define NCLS 3
#define NEG_INF (-INFINITY)

__device__ __forceinline__ float nll3(float l0, float l1, float l2) {
    float m = fmaxf(l0, fmaxf(l1, l2));
    float e0 = __expf(l0 - m);
    float e1 = __expf(l1 - m);
    float e2 = __expf(l2 - m);
    return __logf(e0 + e1 + e2) - (l0 - m);
}

// ---------------------------------------------------------------------------
// Fused negative focal loss over one (TD x TH x TW) tile, software-pipelined:
// logit loads for plane p+1 are issued before the barrier of plane p, so HBM
// latency overlaps the barrier + LDS 3x3 + output work. Double-buffered LDS
// halo planes; 3-deep register sliding window along d for the 3x3x3 NMS.
// ---------------------------------------------------------------------------
template<int TD, int TH, int TW>
__device__ void fused_neg_dev(int bid, int tid,
                              const float* __restrict__ logit,
                              const float* __restrict__ prob_gt,
                              float* __restrict__ out,
                              int A, int D, int H, int W,
                              float* nlp, float* sred) {
    constexpr int NT = TH * TW;
    constexpr int PH = TH + 2, PW = TW + 2, PLANE = PH * PW;

    const int S = D * H * W;
    const int tilesH = H / TH;
    const int tilesD = D / TD;

    const int ht = bid % tilesH; bid /= tilesH;
    const int dt = bid % tilesD; bid /= tilesD;
    const int ba = bid;                 // b*A + a
    const int a = ba % A, b = ba / A;

    const int d0 = dt * TD, h0 = ht * TH;
    const float* lbase = logit + ((long)b * NCLS * A + a) * S;  // class-0 plane
    const long cs = (long)A * S;
    const float* pg = prob_gt + (long)ba * S;

    const int w = tid % TW, h = tid / TW;

    // halo-plane element assignment: up to 2 elements per thread
    const int j0 = tid % PW, i0 = tid / PW;
    const int hh0 = h0 - 1 + i0, ww0 = j0 - 1;
    const bool v0 = (hh0 >= 0) & (hh0 < H) & (ww0 >= 0) & (ww0 < W);
    const long o0 = (long)hh0 * W + ww0;
    const int e1i = tid + NT;
    const bool has1 = e1i < PLANE;
    const int j1 = e1i % PW, i1 = e1i / PW;
    const int hh1 = h0 - 1 + i1, ww1 = j1 - 1;
    const bool v1 = has1 & (hh1 >= 0) & (hh1 < H) & (ww1 >= 0) & (ww1 < W);
    const long o1 = (long)hh1 * W + ww1;

    float a0 = 0, a1 = 0, a2 = 0, b0 = 0, b1 = 0, b2 = 0;

    // prologue prefetch: plane d0-1 and first prob_gt row
    {
        const int d = d0 - 1;
        if (d >= 0) {
            const float* lp = lbase + (long)d * H * W;
            if (v0) { a0 = lp[o0]; a1 = lp[o0 + cs]; a2 = lp[o0 + 2 * cs]; }
            if (v1) { b0 = lp[o1]; b1 = lp[o1 + cs]; b2 = lp[o1 + 2 * cs]; }
        }
    }
    float pgv_next = pg[((long)d0 * H + (h0 + h)) * W + w];

    float hw0 = NEG_INF, hw1 = NEG_INF, c1 = 0.f;
    float loss = 0.f, cnt = 0.f;

    for (int step = -1; step <= TD; ++step) {
        float* buf = nlp + ((step + 1) & 1) * PLANE;
        const int d = d0 + step;
        const bool dv = (d >= 0) & (d < D);
        float r0 = NEG_INF, r1 = NEG_INF;
        if (dv & v0) r0 = nll3(a0, a1, a2);
        if (dv & v1) r1 = nll3(b0, b1, b2);
        buf[tid] = r0;
        if (has1) buf[e1i] = r1;
        // issue loads for the NEXT plane before the barrier (latency overlap)
        if (step < TD) {
            const int dn = d + 1;
            if (dn >= 0 && dn < D) {
                const float* lp = lbase + (long)dn * H * W;
                if (v0) { a0 = lp[o0]; a1 = lp[o0 + cs]; a2 = lp[o0 + 2 * cs]; }
                if (v1) { b0 = lp[o1]; b1 = lp[o1 + cs]; b2 = lp[o1 + 2 * cs]; }
            }
        }
        __syncthreads();

        // 3x3 max centered at (h+1, w+1) of the halo plane
        const float* r0p = buf + h * PW + w;
        const float* r1p = r0p + PW;
        const float* r2p = r1p + PW;
        float m0 = fmaxf(fmaxf(r0p[0], r0p[1]), r0p[2]);
        float m1 = fmaxf(fmaxf(r1p[0], r1p[1]), r1p[2]);
        float m2 = fmaxf(fmaxf(r2p[0], r2p[1]), r2p[2]);
        float hw2 = fmaxf(m0, fmaxf(m1, m2));
        float cc = r1p[1];

        if (step >= 1) {
            float pgv = pgv_next;
            if (step < TD)
                pgv_next = pg[((long)d * H + (h0 + h)) * W + w];
            if (pgv == -1.0f) {
                float mp = fmaxf(hw0, fmaxf(hw1, hw2));
                if (mp == c1) {
                    float pn = __expf(-c1);
                    float wn = (1.f - pn) * (1.f - pn);
                    loss += c1 * wn;
                    cnt  += wn;
                }
            }
        }
        hw0 = hw1; hw1 = hw2; c1 = cc;
    }

    for (int off = 32; off > 0; off >>= 1) {
        loss += __shfl_down(loss, off);
        cnt  += __shfl_down(cnt, off);
    }
    const int wave = tid >> 6, lane = tid & 63;
    if (lane == 0) { sred[wave] = loss; sred[4 + wave] = cnt; }
    __syncthreads();
    if (tid == 0) {
        float L = 0.f, C = 0.f;
        #pragma unroll
        for (int i = 0; i < NT / 64; ++i) { L += sred[i]; C += sred[4 + i]; }
        atomicAdd(&out[1], L);
        atomicAdd(&out[3], C);
    }
}

// ---------------------------------------------------------------------------
// Positive gathers for one level (one 256-thread block, B*P = 512 items).
// ---------------------------------------------------------------------------
__device__ void pos_dev(const float* __restrict__ logit,
                        const float* __restrict__ prob_gt,
                        const int* __restrict__ coord,
                        const float* __restrict__ wcls,
                        float* __restrict__ out,
                        int A, int D, int H, int W, int P) {
    const int S = D * H * W;
    float loss = 0.f, cnt = 0.f;
    for (int i = threadIdx.x; i < 4 * P; i += 256) {
        const int b = i / P;
        const int* c = coord + (long)i * 4;
        const int a = c[0];
        if (a > -1) {
            const int d = c[1], h = c[2], w = c[3];
            const int s = (d * H + h) * W + w;
            const int cls = (int)prob_gt[((long)b * A + a) * S + s];
            const float* lp = logit + ((long)b * NCLS * A + a) * S + s;
            float l0 = lp[0];
            float l1 = lp[(long)A * S];
            float l2 = lp[2L * A * S];
            float m = fmaxf(l0, fmaxf(l1, l2));
            float e0 = __expf(l0 - m);
            float e1 = __expf(l1 - m);
            float e2 = __expf(l2 - m);
            float lsum = __logf(e0 + e1 + e2);
            float lc = (cls == 0) ? l0 : ((cls == 1) ? l1 : l2);
            float lpc = (lc - m) - lsum;
            float pt = __expf(lpc);
            float wp = (1.f - pt) * (1.f - pt) * wcls[cls];
            loss += (-lpc) * wp;
            cnt += wp;
        }
    }
    for (int off = 32; off > 0; off >>= 1) {
        loss += __shfl_down(loss, off);
        cnt  += __shfl_down(cnt, off);
    }
    if ((threadIdx.x & 63) == 0) {
        atomicAdd(&out[0], loss);
        atomicAdd(&out[2], cnt);
    }
}

// ---------------------------------------------------------------------------
// One launch for everything: [0,G0) level-0 neg, [G0,G0+G1) level-1 neg,
// G0+G1 -> level-0 pos, G0+G1+1 -> level-1 pos.
// ---------------------------------------------------------------------------
__global__ __launch_bounds__(256)
void mega_kernel(const float* __restrict__ logit0,
                 const float* __restrict__ logit1,
                 const float* __restrict__ pg0,
                 const float* __restrict__ pg1,
                 const int* __restrict__ coord0,
                 const int* __restrict__ coord1,
                 const float* __restrict__ wcls,
                 float* __restrict__ out,
                 int G0, int G1) {
    __shared__ float nlp[2 * 396];   // max halo plane: (4+2)*(64+2)=396
    __shared__ float sred[8];
    const int bid = blockIdx.x;
    if (bid < G0) {
        fused_neg_dev<4, 4, 64>(bid, threadIdx.x, logit0, pg0, out,
                                3, 64, 64, 64, nlp, sred);
    } else if (bid < G0 + G1) {
        fused_neg_dev<4, 8, 32>(bid - G0, threadIdx.x, logit1, pg1, out,
                                3, 32, 32, 32, nlp, sred);
    } else if (bid == G0 + G1) {
        pos_dev(logit0, pg0, coord0, wcls, out, 3, 64, 64, 64, 128);
    } else {
        pos_dev(logit1, pg1, coord1, wcls, out, 3, 32, 32, 32, 128);
    }
}

extern "C" void kernel_launch(void* const* d_in, const int* in_sizes, int n_in,
                              void* d_out, int out_size, void* d_ws, size_t ws_size,
                              hipStream_t stream) {
    const float* logit0   = (const float*)d_in[0];
    const float* logit1   = (const float*)d_in[1];
    const float* prob_gt0 = (const float*)d_in[2];
    const float* prob_gt1 = (const float*)d_in[3];
    const int*   coord0   = (const int*)d_in[4];
    const int*   coord1   = (const int*)d_in[5];
    const float* wcls     = (const float*)d_in[6];
    float* out = (float*)d_out;

    // Level 0: B*A=12, tilesD=64/4=16, tilesH=64/4=16 -> 3072 blocks
    // Level 1: B*A=12, tilesD=32/4=8,  tilesH=32/8=4  ->  384 blocks
    const int G0 = 3072, G1 = 384;

    hipMemsetAsync(out, 0, 4 * sizeof(float), stream);
    mega_kernel<<<G0 + G1 + 2, 256, 0, stream>>>(
        logit0, logit1, prob_gt0, prob_gt1, coord0, coord1, wcls, out, G0, G1);
}